// Round 2
// baseline (2365.819 us; speedup 1.0000x reference)
//
#include <hip/hip_runtime.h>
#include <hip/hip_bf16.h>

// MultiHeadCA: B=4, T=2048, D_MODEL=1024, N_HEADS=16, HEAD=64
// All global tensors are FLOAT32 (per reference). Pipeline:
//   kv  = x_enc @ Wkv + bkv          (8192x1024 @ 1024x2048)
//   q   = x_dec @ Wq  + bq           (8192x1024 @ 1024x1024)
//   per (b,h): attn = softmax(qk^T/8 + mask); res = attn @ v
//   out = res @ Wo + bo              (8192x1024 @ 1024x1024)
// Intermediates fp32 in d_ws (134.2 MB).

#define D_MODEL 1024
#define NH      16
#define HEAD    64
#define BATCH   4
#define SEQ     2048

// ---------------- GEMM: A(f32) MxK @ W(f32) KxN + bias(f32) -> C(f32) -------
// 128x128 block tile, BK=16, 256 threads, 8x8 per-thread register tile.
__global__ __launch_bounds__(256) void gemm_f32(
    const float* __restrict__ A, const float* __restrict__ W,
    const float* __restrict__ bias, float* __restrict__ C,
    int N, int K)
{
    __shared__ float As[16][132];
    __shared__ float Bs[16][132];
    const int t  = threadIdx.x;
    const int n0 = blockIdx.x * 128;
    const int m0 = blockIdx.y * 128;
    const int tx = t & 15, ty = t >> 4;
    const int lm = t >> 1, lk = (t & 1) * 8;   // A-stage: row m=lm, k=lk..lk+7
    const int wk = t >> 4, wn = (t & 15) * 8;  // W-stage: row k=wk, n=wn..wn+7

    const float* Ap = A + (size_t)(m0 + lm) * K + lk;
    const float* Wp = W + (size_t)wk * N + n0 + wn;

    float acc[8][8];
    #pragma unroll
    for (int i = 0; i < 8; ++i)
        #pragma unroll
        for (int j = 0; j < 8; ++j) acc[i][j] = 0.f;

    for (int k0 = 0; k0 < K; k0 += 16) {
        float4 a0 = *(const float4*)Ap;
        float4 a1 = *(const float4*)(Ap + 4);
        float4 w0 = *(const float4*)Wp;
        float4 w1 = *(const float4*)(Wp + 4);
        Ap += 16;
        Wp += (size_t)16 * N;
        As[lk+0][lm] = a0.x; As[lk+1][lm] = a0.y;
        As[lk+2][lm] = a0.z; As[lk+3][lm] = a0.w;
        As[lk+4][lm] = a1.x; As[lk+5][lm] = a1.y;
        As[lk+6][lm] = a1.z; As[lk+7][lm] = a1.w;
        *(float4*)&Bs[wk][wn]     = w0;
        *(float4*)&Bs[wk][wn + 4] = w1;
        __syncthreads();
        #pragma unroll
        for (int k = 0; k < 16; ++k) {
            float a[8], w[8];
            *(float4*)&a[0] = *(const float4*)&As[k][ty*8];
            *(float4*)&a[4] = *(const float4*)&As[k][ty*8+4];
            *(float4*)&w[0] = *(const float4*)&Bs[k][tx*8];
            *(float4*)&w[4] = *(const float4*)&Bs[k][tx*8+4];
            #pragma unroll
            for (int i = 0; i < 8; ++i)
                #pragma unroll
                for (int j = 0; j < 8; ++j)
                    acc[i][j] = fmaf(a[i], w[j], acc[i][j]);
        }
        __syncthreads();
    }
    float bv[8];
    #pragma unroll
    for (int j = 0; j < 8; ++j) bv[j] = bias[n0 + tx*8 + j];
    #pragma unroll
    for (int i = 0; i < 8; ++i) {
        float* Cp = C + (size_t)(m0 + ty*8 + i) * N + n0 + tx*8;
        *(float4*)Cp     = make_float4(acc[i][0]+bv[0], acc[i][1]+bv[1],
                                       acc[i][2]+bv[2], acc[i][3]+bv[3]);
        *(float4*)(Cp+4) = make_float4(acc[i][4]+bv[4], acc[i][5]+bv[5],
                                       acc[i][6]+bv[6], acc[i][7]+bv[7]);
    }
}

// ---------------- Flash attention (fp32), one WG per (b, h, 64-row q block) -
// Q: f32 8192x1024 (col = h*64+d); KV: f32 8192x2048 (head h: cols h*128..+63
// are K, h*128+64..+127 are V); mask f32 (B,T,T); R: f32 8192x1024.
// K-tile = 32 rows. LDS: Qs 17.0K + Ks 8.5K + Vs 8.5K + Ps 9.0K = 43 KB.
__global__ __launch_bounds__(256) void attn_kernel(
    const float* __restrict__ Q, const float* __restrict__ KV,
    const float* __restrict__ mask, float* __restrict__ R)
{
    __shared__ float Qs[64][68];
    __shared__ float Ks[32][68];
    __shared__ float Vs[32][68];
    __shared__ float Ps[64][36];
    const int t  = threadIdx.x;
    const int q0 = blockIdx.x * 64;
    const int h  = blockIdx.y;
    const int b  = blockIdx.z;
    const int tx = t & 15, ty = t >> 4;
    // S tile per thread: rows ty*4..+3 (of 64), cols tx*2..+1 (of 32)
    // O tile per thread: rows ty*4..+3, d-cols tx*4..+3 (of 64)

    {   // load Q tile 64x64
        const int qr = t >> 2, qc = (t & 3) * 16;
        const float* Qp = Q + (size_t)(b*SEQ + q0 + qr) * D_MODEL + h*HEAD + qc;
        #pragma unroll
        for (int j = 0; j < 4; ++j)
            *(float4*)&Qs[qr][qc + 4*j] = *(const float4*)(Qp + 4*j);
    }
    float m_i[4], l_i[4], o[4][4];
    #pragma unroll
    for (int i = 0; i < 4; ++i) {
        m_i[i] = -INFINITY; l_i[i] = 0.f;
        #pragma unroll
        for (int j = 0; j < 4; ++j) o[i][j] = 0.f;
    }
    __syncthreads();

    for (int k0 = 0; k0 < SEQ; k0 += 32) {
        {   // load K,V tiles 32x64 each
            const int kr = t >> 3, kc = (t & 7) * 8;
            const float* KVp = KV + (size_t)(b*SEQ + k0 + kr) * (2*D_MODEL) + h*2*HEAD;
            *(float4*)&Ks[kr][kc]     = *(const float4*)(KVp + kc);
            *(float4*)&Ks[kr][kc + 4] = *(const float4*)(KVp + kc + 4);
            *(float4*)&Vs[kr][kc]     = *(const float4*)(KVp + HEAD + kc);
            *(float4*)&Vs[kr][kc + 4] = *(const float4*)(KVp + HEAD + kc + 4);
        }
        __syncthreads();

        // S = Q K^T   (64x32 tile; per thread 4x2)
        float s[4][2] = {{0.f,0.f},{0.f,0.f},{0.f,0.f},{0.f,0.f}};
        #pragma unroll
        for (int d4 = 0; d4 < HEAD; d4 += 4) {
            float qv[4][4], kv[2][4];
            #pragma unroll
            for (int i = 0; i < 4; ++i)
                *(float4*)qv[i] = *(const float4*)&Qs[ty*4+i][d4];
            #pragma unroll
            for (int j = 0; j < 2; ++j)
                *(float4*)kv[j] = *(const float4*)&Ks[tx*2+j][d4];
            #pragma unroll
            for (int i = 0; i < 4; ++i)
                #pragma unroll
                for (int j = 0; j < 2; ++j)
                    s[i][j] += qv[i][0]*kv[j][0] + qv[i][1]*kv[j][1]
                             + qv[i][2]*kv[j][2] + qv[i][3]*kv[j][3];
        }
        // scale + mask, online softmax (row group = 16 lanes sharing ty)
        #pragma unroll
        for (int i = 0; i < 4; ++i) {
            const float* Mp = mask + ((size_t)b*SEQ + (q0 + ty*4 + i)) * SEQ + k0 + tx*2;
            float2 mv = *(const float2*)Mp;
            s[i][0] = s[i][0]*0.125f + mv.x;
            s[i][1] = s[i][1]*0.125f + mv.y;

            float rm = fmaxf(s[i][0], s[i][1]);
            rm = fmaxf(rm, __shfl_xor(rm, 1, 16));
            rm = fmaxf(rm, __shfl_xor(rm, 2, 16));
            rm = fmaxf(rm, __shfl_xor(rm, 4, 16));
            rm = fmaxf(rm, __shfl_xor(rm, 8, 16));
            float mn = fmaxf(m_i[i], rm);
            float alpha = __expf(m_i[i] - mn);
            m_i[i] = mn;
            float p0 = __expf(s[i][0] - mn);
            float p1 = __expf(s[i][1] - mn);
            float rs = p0 + p1;
            rs += __shfl_xor(rs, 1, 16);
            rs += __shfl_xor(rs, 2, 16);
            rs += __shfl_xor(rs, 4, 16);
            rs += __shfl_xor(rs, 8, 16);
            l_i[i] = l_i[i] * alpha + rs;
            #pragma unroll
            for (int j = 0; j < 4; ++j) o[i][j] *= alpha;
            *(float2*)&Ps[ty*4+i][tx*2] = make_float2(p0, p1);
        }
        __syncthreads();

        // O += P @ V   (64x32 @ 32x64; per thread 4 rows x 4 d-cols)
        #pragma unroll
        for (int kk = 0; kk < 32; kk += 4) {
            float pv[4][4], vv[4][4];
            #pragma unroll
            for (int i = 0; i < 4; ++i)
                *(float4*)pv[i] = *(const float4*)&Ps[ty*4+i][kk];
            #pragma unroll
            for (int r = 0; r < 4; ++r)
                *(float4*)vv[r] = *(const float4*)&Vs[kk+r][tx*4];
            #pragma unroll
            for (int i = 0; i < 4; ++i)
                #pragma unroll
                for (int j = 0; j < 4; ++j)
                    o[i][j] += pv[i][0]*vv[0][j] + pv[i][1]*vv[1][j]
                             + pv[i][2]*vv[2][j] + pv[i][3]*vv[3][j];
        }
        __syncthreads();
    }
    #pragma unroll
    for (int i = 0; i < 4; ++i) {
        float inv = 1.0f / l_i[i];
        *(float4*)&R[(size_t)(b*SEQ + q0 + ty*4 + i) * D_MODEL + h*HEAD + tx*4] =
            make_float4(o[i][0]*inv, o[i][1]*inv, o[i][2]*inv, o[i][3]*inv);
    }
}

extern "C" void kernel_launch(void* const* d_in, const int* in_sizes, int n_in,
                              void* d_out, int out_size, void* d_ws, size_t ws_size,
                              hipStream_t stream) {
    const float* x_enc = (const float*)d_in[0];
    const float* x_dec = (const float*)d_in[1];
    const float* mask  = (const float*)d_in[2];
    const float* Wq    = (const float*)d_in[3];
    const float* bq    = (const float*)d_in[4];
    const float* Wkv   = (const float*)d_in[5];
    const float* bkv   = (const float*)d_in[6];
    const float* Wo    = (const float*)d_in[7];
    const float* bo    = (const float*)d_in[8];
    float* out = (float*)d_out;

    const int M = BATCH * SEQ;                 // 8192
    float* q_buf   = (float*)d_ws;                       // 8192x1024 f32 (33.5 MB)
    float* kv_buf  = q_buf + (size_t)M * D_MODEL;        // 8192x2048 f32 (67.1 MB)
    float* res_buf = kv_buf + (size_t)M * 2 * D_MODEL;   // 8192x1024 f32 (33.5 MB)

    gemm_f32<<<dim3(2*D_MODEL/128, M/128), 256, 0, stream>>>(
        x_enc, Wkv, bkv, kv_buf, 2*D_MODEL, D_MODEL);
    gemm_f32<<<dim3(D_MODEL/128, M/128), 256, 0, stream>>>(
        x_dec, Wq, bq, q_buf, D_MODEL, D_MODEL);
    attn_kernel<<<dim3(SEQ/64, NH, BATCH), 256, 0, stream>>>(
        q_buf, kv_buf, mask, res_buf);
    gemm_f32<<<dim3(D_MODEL/128, M/128), 256, 0, stream>>>(
        res_buf, Wo, bo, out, D_MODEL, D_MODEL);
}

// Round 3
// 676.828 us; speedup vs baseline: 3.4954x; 3.4954x over previous
//
#include <hip/hip_runtime.h>
#include <hip/hip_bf16.h>

// MultiHeadCA bf16-MFMA pipeline. B=4, T=2048, D=1024, NH=16, HEAD=64.
//   prep:  cast x -> bf16; W -> W^T bf16 (m97 GEMM wants B^T rows)
//   kv  = x_enc @ Wkv + bkv   (bf16 MFMA, out bf16)
//   q   = x_dec @ Wq  + bq    (bf16 MFMA, out bf16)
//   v_t = transpose of V heads -> [b,h,d,t] (PV B-operand wants contiguous k)
//   attn: flash MFMA, res bf16
//   out = res @ Wo + bo       (bf16 MFMA, out f32)

#define D_MODEL 1024
#define NH      16
#define HEAD    64
#define BATCH   4
#define SEQ     2048

typedef unsigned int   u32;
typedef unsigned short u16;
typedef __attribute__((ext_vector_type(8))) short s16x8;   // 8 bf16 (4 VGPRs)
typedef __attribute__((ext_vector_type(4))) float f32x4;   // MFMA C/D

__device__ __forceinline__ u16 tobf(float f) {   // RNE f32->bf16
    u32 u = __builtin_bit_cast(u32, f);
    return (u16)((u + 0x7fffu + ((u >> 16) & 1u)) >> 16);
}

__device__ __forceinline__ void gl_lds16(const void* g, void* l) {
    __builtin_amdgcn_global_load_lds(
        (const __attribute__((address_space(1))) u32*)g,
        (__attribute__((address_space(3))) u32*)l, 16, 0, 0);
}

// ---------------- cast f32 -> bf16 ----------------
__global__ __launch_bounds__(256) void cast_bf16(
    const float* __restrict__ in, u16* __restrict__ out, int n)
{
    int i = (blockIdx.x * 256 + threadIdx.x) * 4;
    if (i < n) {
        float4 v = *(const float4*)(in + i);
        ushort4 o = make_ushort4(tobf(v.x), tobf(v.y), tobf(v.z), tobf(v.w));
        *(ushort4*)(out + i) = o;
    }
}

// ---------------- W (KxN f32) -> W^T (NxK bf16) ----------------
__global__ __launch_bounds__(256) void transpose_cast(
    const float* __restrict__ W, u16* __restrict__ WT, int K, int N)
{
    __shared__ __align__(16) float tile[32][33];
    const int n0 = blockIdx.x * 32, k0 = blockIdx.y * 32;
    const int r = threadIdx.x >> 3, c4 = (threadIdx.x & 7) * 4;
    float4 v = *(const float4*)&W[(size_t)(k0 + r) * N + n0 + c4];
    tile[r][c4] = v.x; tile[r][c4+1] = v.y; tile[r][c4+2] = v.z; tile[r][c4+3] = v.w;
    __syncthreads();
    ushort4 o = make_ushort4(tobf(tile[c4+0][r]), tobf(tile[c4+1][r]),
                             tobf(tile[c4+2][r]), tobf(tile[c4+3][r]));
    *(ushort4*)&WT[(size_t)(n0 + r) * K + k0 + c4] = o;
}

// ---------------- m97-style GEMM: A(MxK bf16) @ Bt(NxK bf16)^T + bias -> C --
// 128x128 tile, BK=32, 256 thr = 4 waves in 2x2, 4x4 MFMA tiles/wave.
__device__ __forceinline__ void store_out(u16* p, float v)  { *p = tobf(v); }
__device__ __forceinline__ void store_out(float* p, float v){ *p = v; }

template <typename OT>
__global__ __launch_bounds__(256) void gemm_bt(
    const u16* __restrict__ A, const u16* __restrict__ Bt,
    const float* __restrict__ bias, OT* __restrict__ C,
    int N, int K)
{
    __shared__ __align__(16) u16 As[128 * 32];   // row-major, NO pad (global_load_lds)
    __shared__ __align__(16) u16 Bs[128 * 32];
    const int t = threadIdx.x;
    const int w = t >> 6, l = t & 63;
    const int lane15 = l & 15, quad = l >> 4;
    const int m0 = blockIdx.y * 128, n0 = blockIdx.x * 128;
    const int wm = (w >> 1) * 64, wn = (w & 1) * 64;
    const int lr = l >> 2, lk = (l & 3) * 8;   // staging: row-in-16, k-offset

    f32x4 acc[4][4] = {};

    for (int k0 = 0; k0 < K; k0 += 32) {
        __syncthreads();
        #pragma unroll
        for (int i = 0; i < 2; ++i) {
            const int chunk = w * 2 + i;             // 16-row chunk id (0..7)
            gl_lds16(A  + (size_t)(m0 + chunk*16 + lr) * K + k0 + lk,
                     As + chunk * 512);
            gl_lds16(Bt + (size_t)(n0 + chunk*16 + lr) * K + k0 + lk,
                     Bs + chunk * 512);
        }
        __syncthreads();
        s16x8 af[4], bfr[4];
        #pragma unroll
        for (int i = 0; i < 4; ++i)
            af[i] = *(const s16x8*)&As[(wm + i*16 + lane15) * 32 + quad * 8];
        #pragma unroll
        for (int j = 0; j < 4; ++j)
            bfr[j] = *(const s16x8*)&Bs[(wn + j*16 + lane15) * 32 + quad * 8];
        #pragma unroll
        for (int i = 0; i < 4; ++i)
            #pragma unroll
            for (int j = 0; j < 4; ++j)
                acc[i][j] = __builtin_amdgcn_mfma_f32_16x16x32_bf16(
                    af[i], bfr[j], acc[i][j], 0, 0, 0);
    }
    #pragma unroll
    for (int j = 0; j < 4; ++j) {
        const int col = n0 + wn + j*16 + lane15;
        const float bv = bias[col];
        #pragma unroll
        for (int i = 0; i < 4; ++i)
            #pragma unroll
            for (int r = 0; r < 4; ++r) {
                const int row = m0 + wm + i*16 + quad*4 + r;
                store_out(C + (size_t)row * N + col, acc[i][j][r] + bv);
            }
    }
}

// ---------------- V head transpose: kv[b,t,h*128+64+d] -> vt[(bh*64+d)*T+t] -
__global__ __launch_bounds__(256) void v_transpose(
    const u16* __restrict__ kvb, u16* __restrict__ vt)
{
    __shared__ __align__(16) u16 tile[64][72];
    const int t  = threadIdx.x;
    const int t0 = blockIdx.x * 64;
    const int bh = blockIdx.y;
    const int b = bh >> 4, h = bh & 15;
    const int r = t >> 2, c = (t & 3) * 16;
    const u16* g = kvb + (size_t)(b*SEQ + t0 + r) * (2*D_MODEL) + h*128 + 64 + c;
    *(uint4*)&tile[r][c]     = *(const uint4*)g;
    *(uint4*)&tile[r][c + 8] = *(const uint4*)(g + 8);
    __syncthreads();
    u16 buf[16];
    #pragma unroll
    for (int i = 0; i < 16; ++i) buf[i] = tile[c + i][r];
    u16* o = vt + (size_t)(bh*64 + r) * SEQ + t0 + c;
    *(uint4*)o       = *(uint4*)&buf[0];
    *(uint4*)(o + 8) = *(uint4*)&buf[8];
}

// ---------------- MFMA flash attention ----------------
// WG = (64 q-rows, h, b); 4 waves x 16 q-rows. K-tile 64. Online softmax in
// C/D layout (col=lane&15, row=quad*4+reg); P -> LDS -> A-layout (guide SSB).
__global__ __launch_bounds__(256) void attn_mfma(
    const u16* __restrict__ qb, const u16* __restrict__ kvb,
    const u16* __restrict__ vt, const float* __restrict__ mask,
    u16* __restrict__ resb)
{
    __shared__ __align__(16) u16 Qs[64][72];
    __shared__ __align__(16) u16 Ks[64][72];
    __shared__ __align__(16) u16 Vs[64][72];      // V^T tile: [d][k]
    __shared__ __align__(16) u16 Ps[4][16][72];   // per-wave P
    const int t = threadIdx.x;
    const int w = t >> 6, l = t & 63;
    const int lane15 = l & 15, quad = l >> 4;
    const int q0 = blockIdx.x * 64;
    const int h = blockIdx.y, b = blockIdx.z;
    const int bh = b * NH + h;
    const int sr = t >> 2, sc = (t & 3) * 16;

    {   // stage Q once
        const u16* g = qb + (size_t)(b*SEQ + q0 + sr) * D_MODEL + h*HEAD + sc;
        *(uint4*)&Qs[sr][sc]     = *(const uint4*)g;
        *(uint4*)&Qs[sr][sc + 8] = *(const uint4*)(g + 8);
    }
    __syncthreads();
    s16x8 aq0 = *(const s16x8*)&Qs[w*16 + lane15][quad*8];
    s16x8 aq1 = *(const s16x8*)&Qs[w*16 + lane15][32 + quad*8];

    f32x4 o_acc[4] = {};
    float m_i[4], l_i[4];
    #pragma unroll
    for (int r = 0; r < 4; ++r) { m_i[r] = -INFINITY; l_i[r] = 0.f; }

    const size_t mrow0 = ((size_t)b*SEQ + q0 + w*16 + quad*4) * SEQ;

    for (int k0 = 0; k0 < SEQ; k0 += 64) {
        __syncthreads();
        {   // stage K (row-major [k][d]) and V^T ([d][k]) tiles
            const u16* kg = kvb + (size_t)(b*SEQ + k0 + sr) * (2*D_MODEL) + h*128 + sc;
            *(uint4*)&Ks[sr][sc]     = *(const uint4*)kg;
            *(uint4*)&Ks[sr][sc + 8] = *(const uint4*)(kg + 8);
            const u16* vg = vt + (size_t)(bh*64 + sr) * SEQ + k0 + sc;
            *(uint4*)&Vs[sr][sc]     = *(const uint4*)vg;
            *(uint4*)&Vs[sr][sc + 8] = *(const uint4*)(vg + 8);
        }
        __syncthreads();

        // S = Q K^T (16 x 64 per wave)
        f32x4 s[4];
        #pragma unroll
        for (int nt = 0; nt < 4; ++nt) {
            s16x8 b0 = *(const s16x8*)&Ks[nt*16 + lane15][quad*8];
            s16x8 b1 = *(const s16x8*)&Ks[nt*16 + lane15][32 + quad*8];
            f32x4 z = {};
            z = __builtin_amdgcn_mfma_f32_16x16x32_bf16(aq0, b0, z, 0, 0, 0);
            s[nt] = __builtin_amdgcn_mfma_f32_16x16x32_bf16(aq1, b1, z, 0, 0, 0);
        }
        // scale + mask + online softmax; row r of tile = quad*4 + r
        float alpha[4];
        #pragma unroll
        for (int r = 0; r < 4; ++r) {
            const float* mp = mask + mrow0 + (size_t)r * SEQ + k0 + lane15;
            float sv[4];
            #pragma unroll
            for (int nt = 0; nt < 4; ++nt)
                sv[nt] = s[nt][r] * 0.125f + mp[nt * 16];
            float mx = fmaxf(fmaxf(sv[0], sv[1]), fmaxf(sv[2], sv[3]));
            mx = fmaxf(mx, __shfl_xor(mx, 1));
            mx = fmaxf(mx, __shfl_xor(mx, 2));
            mx = fmaxf(mx, __shfl_xor(mx, 4));
            mx = fmaxf(mx, __shfl_xor(mx, 8));
            float mn = fmaxf(m_i[r], mx);
            alpha[r] = __expf(m_i[r] - mn);
            m_i[r] = mn;
            float rs = 0.f;
            #pragma unroll
            for (int nt = 0; nt < 4; ++nt) {
                float p = __expf(sv[nt] - mn);
                s[nt][r] = p;
                rs += p;
            }
            rs += __shfl_xor(rs, 1);
            rs += __shfl_xor(rs, 2);
            rs += __shfl_xor(rs, 4);
            rs += __shfl_xor(rs, 8);
            l_i[r] = l_i[r] * alpha[r] + rs;
        }
        // P (C/D layout) -> LDS as bf16 (per-wave buffer; wave LDS ops in-order)
        #pragma unroll
        for (int nt = 0; nt < 4; ++nt)
            #pragma unroll
            for (int r = 0; r < 4; ++r)
                Ps[w][quad*4 + r][nt*16 + lane15] = tobf(s[nt][r]);
        #pragma unroll
        for (int dt = 0; dt < 4; ++dt)
            #pragma unroll
            for (int r = 0; r < 4; ++r)
                o_acc[dt][r] *= alpha[r];
        // O += P @ V  (P as A-operand from LDS; V^T rows as B-operand)
        s16x8 ap0 = *(const s16x8*)&Ps[w][lane15][quad*8];
        s16x8 ap1 = *(const s16x8*)&Ps[w][lane15][32 + quad*8];
        #pragma unroll
        for (int dt = 0; dt < 4; ++dt) {
            s16x8 b0 = *(const s16x8*)&Vs[dt*16 + lane15][quad*8];
            s16x8 b1 = *(const s16x8*)&Vs[dt*16 + lane15][32 + quad*8];
            o_acc[dt] = __builtin_amdgcn_mfma_f32_16x16x32_bf16(ap0, b0, o_acc[dt], 0, 0, 0);
            o_acc[dt] = __builtin_amdgcn_mfma_f32_16x16x32_bf16(ap1, b1, o_acc[dt], 0, 0, 0);
        }
    }
    #pragma unroll
    for (int r = 0; r < 4; ++r) {
        const float inv = 1.f / l_i[r];
        const size_t row = (size_t)b*SEQ + q0 + w*16 + quad*4 + r;
        #pragma unroll
        for (int dt = 0; dt < 4; ++dt)
            resb[row * D_MODEL + h*HEAD + dt*16 + lane15] = tobf(o_acc[dt][r] * inv);
    }
}

extern "C" void kernel_launch(void* const* d_in, const int* in_sizes, int n_in,
                              void* d_out, int out_size, void* d_ws, size_t ws_size,
                              hipStream_t stream) {
    const float* x_enc = (const float*)d_in[0];
    const float* x_dec = (const float*)d_in[1];
    const float* mask  = (const float*)d_in[2];
    const float* Wq    = (const float*)d_in[3];
    const float* bq    = (const float*)d_in[4];
    const float* Wkv   = (const float*)d_in[5];
    const float* bkv   = (const float*)d_in[6];
    const float* Wo    = (const float*)d_in[7];
    const float* bo    = (const float*)d_in[8];
    float* out = (float*)d_out;

    const int M = BATCH * SEQ;  // 8192
    u16* xe   = (u16*)d_ws;                       // 8192x1024
    u16* xd   = xe   + (size_t)M * D_MODEL;       // 8192x1024
    u16* wqT  = xd   + (size_t)M * D_MODEL;       // 1024x1024
    u16* wkvT = wqT  + (size_t)D_MODEL * D_MODEL; // 2048x1024
    u16* woT  = wkvT + (size_t)2*D_MODEL*D_MODEL; // 1024x1024
    u16* qbuf = woT  + (size_t)D_MODEL * D_MODEL; // 8192x1024
    u16* kvb  = qbuf + (size_t)M * D_MODEL;       // 8192x2048
    u16* vtb  = kvb  + (size_t)M * 2 * D_MODEL;   // 64x64x2048
    u16* resb = vtb  + (size_t)BATCH*NH*HEAD*SEQ; // 8192x1024
    // total: ~125.8 MB (< 134.2 MB used in R2)

    const int NX = M * D_MODEL;  // 8388608
    cast_bf16<<<NX/1024, 256, 0, stream>>>(x_enc, xe, NX);
    cast_bf16<<<NX/1024, 256, 0, stream>>>(x_dec, xd, NX);
    transpose_cast<<<dim3(D_MODEL/32, D_MODEL/32), 256, 0, stream>>>(Wq,  wqT,  D_MODEL, D_MODEL);
    transpose_cast<<<dim3(2*D_MODEL/32, D_MODEL/32), 256, 0, stream>>>(Wkv, wkvT, D_MODEL, 2*D_MODEL);
    transpose_cast<<<dim3(D_MODEL/32, D_MODEL/32), 256, 0, stream>>>(Wo,  woT,  D_MODEL, D_MODEL);

    gemm_bt<u16><<<dim3(2*D_MODEL/128, M/128), 256, 0, stream>>>(
        xe, wkvT, bkv, kvb, 2*D_MODEL, D_MODEL);
    gemm_bt<u16><<<dim3(D_MODEL/128, M/128), 256, 0, stream>>>(
        xd, wqT, bq, qbuf, D_MODEL, D_MODEL);
    v_transpose<<<dim3(SEQ/64, BATCH*NH), 256, 0, stream>>>(kvb, vtb);
    attn_mfma<<<dim3(SEQ/64, NH, BATCH), 256, 0, stream>>>(
        qbuf, kvb, vtb, mask, resb);
    gemm_bt<float><<<dim3(D_MODEL/128, M/128), 256, 0, stream>>>(
        resb, woT, bo, out, D_MODEL, D_MODEL);
}

// Round 5
// 500.728 us; speedup vs baseline: 4.7248x; 1.3517x over previous
//
#include <hip/hip_runtime.h>
#include <hip/hip_bf16.h>

// MultiHeadCA bf16-MFMA pipeline, transposed flash attention.
// B=4, T=2048, D=1024, NH=16, HEAD=64.

#define D_MODEL 1024
#define NH      16
#define HEAD    64
#define BATCH   4
#define SEQ     2048

typedef unsigned int   u32;
typedef unsigned short u16;
typedef __attribute__((ext_vector_type(8))) short s16x8;   // 8 bf16 (4 VGPRs)
typedef __attribute__((ext_vector_type(4))) float f32x4;   // MFMA C/D

__device__ __forceinline__ u16 tobf(float f) {   // RNE f32->bf16
    u32 u = __builtin_bit_cast(u32, f);
    return (u16)((u + 0x7fffu + ((u >> 16) & 1u)) >> 16);
}

__device__ __forceinline__ void gl_lds16(const void* g, void* l) {
    __builtin_amdgcn_global_load_lds(
        (const __attribute__((address_space(1))) u32*)g,
        (__attribute__((address_space(3))) u32*)l, 16, 0, 0);
}

// ---------------- cast f32 -> bf16 ----------------
__global__ __launch_bounds__(256) void cast_bf16(
    const float* __restrict__ in, u16* __restrict__ out, int n)
{
    int i = (blockIdx.x * 256 + threadIdx.x) * 4;
    if (i < n) {
        float4 v = *(const float4*)(in + i);
        ushort4 o = make_ushort4(tobf(v.x), tobf(v.y), tobf(v.z), tobf(v.w));
        *(ushort4*)(out + i) = o;
    }
}

// ---------------- W (KxN f32) -> W^T (NxK bf16) ----------------
__global__ __launch_bounds__(256) void transpose_cast(
    const float* __restrict__ W, u16* __restrict__ WT, int K, int N)
{
    __shared__ __align__(16) float tile[32][33];
    const int n0 = blockIdx.x * 32, k0 = blockIdx.y * 32;
    const int r = threadIdx.x >> 3, c4 = (threadIdx.x & 7) * 4;
    float4 v = *(const float4*)&W[(size_t)(k0 + r) * N + n0 + c4];
    tile[r][c4] = v.x; tile[r][c4+1] = v.y; tile[r][c4+2] = v.z; tile[r][c4+3] = v.w;
    __syncthreads();
    ushort4 o = make_ushort4(tobf(tile[c4+0][r]), tobf(tile[c4+1][r]),
                             tobf(tile[c4+2][r]), tobf(tile[c4+3][r]));
    *(ushort4*)&WT[(size_t)(n0 + r) * K + k0 + c4] = o;
}

// ---------------- m97-style GEMM: A(MxK bf16) @ Bt(NxK bf16)^T + bias -> C --
__device__ __forceinline__ void store_out(u16* p, float v)  { *p = tobf(v); }
__device__ __forceinline__ void store_out(float* p, float v){ *p = v; }

template <typename OT>
__global__ __launch_bounds__(256) void gemm_bt(
    const u16* __restrict__ A, const u16* __restrict__ Bt,
    const float* __restrict__ bias, OT* __restrict__ C,
    int N, int K, float out_scale)
{
    __shared__ __align__(16) u16 As[128 * 32];   // row-major, NO pad (global_load_lds)
    __shared__ __align__(16) u16 Bs[128 * 32];
    const int t = threadIdx.x;
    const int w = t >> 6, l = t & 63;
    const int lane15 = l & 15, quad = l >> 4;
    const int m0 = blockIdx.y * 128, n0 = blockIdx.x * 128;
    const int wm = (w >> 1) * 64, wn = (w & 1) * 64;
    const int lr = l >> 2, lk = (l & 3) * 8;

    f32x4 acc[4][4] = {};

    for (int k0 = 0; k0 < K; k0 += 32) {
        __syncthreads();
        #pragma unroll
        for (int i = 0; i < 2; ++i) {
            const int chunk = w * 2 + i;
            gl_lds16(A  + (size_t)(m0 + chunk*16 + lr) * K + k0 + lk,
                     As + chunk * 512);
            gl_lds16(Bt + (size_t)(n0 + chunk*16 + lr) * K + k0 + lk,
                     Bs + chunk * 512);
        }
        __syncthreads();
        s16x8 af[4], bfr[4];
        #pragma unroll
        for (int i = 0; i < 4; ++i)
            af[i] = *(const s16x8*)&As[(wm + i*16 + lane15) * 32 + quad * 8];
        #pragma unroll
        for (int j = 0; j < 4; ++j)
            bfr[j] = *(const s16x8*)&Bs[(wn + j*16 + lane15) * 32 + quad * 8];
        #pragma unroll
        for (int i = 0; i < 4; ++i)
            #pragma unroll
            for (int j = 0; j < 4; ++j)
                acc[i][j] = __builtin_amdgcn_mfma_f32_16x16x32_bf16(
                    af[i], bfr[j], acc[i][j], 0, 0, 0);
    }
    #pragma unroll
    for (int j = 0; j < 4; ++j) {
        const int col = n0 + wn + j*16 + lane15;
        const float bv = bias[col];
        #pragma unroll
        for (int i = 0; i < 4; ++i)
            #pragma unroll
            for (int r = 0; r < 4; ++r) {
                const int row = m0 + wm + i*16 + quad*4 + r;
                store_out(C + (size_t)row * N + col, (acc[i][j][r] + bv) * out_scale);
            }
    }
}

// ---------------- V head transpose: kv[b,t,h*128+64+d] -> vt[(bh*64+d)*T+t] -
__global__ __launch_bounds__(256) void v_transpose(
    const u16* __restrict__ kvb, u16* __restrict__ vt)
{
    __shared__ __align__(16) u16 tile[64][72];
    const int t  = threadIdx.x;
    const int t0 = blockIdx.x * 64;
    const int bh = blockIdx.y;
    const int b = bh >> 4, h = bh & 15;
    const int r = t >> 2, c = (t & 3) * 16;
    const u16* g = kvb + (size_t)(b*SEQ + t0 + r) * (2*D_MODEL) + h*128 + 64 + c;
    *(uint4*)&tile[r][c]     = *(const uint4*)g;
    *(uint4*)&tile[r][c + 8] = *(const uint4*)(g + 8);
    __syncthreads();
    u16 buf[16];
    #pragma unroll
    for (int i = 0; i < 16; ++i) buf[i] = tile[c + i][r];
    u16* o = vt + (size_t)(bh*64 + r) * SEQ + t0 + c;
    *(uint4*)o       = *(uint4*)&buf[0];
    *(uint4*)(o + 8) = *(uint4*)&buf[8];
}

// ---------------- Transposed MFMA flash attention ----------------
// WG = (64 q-rows, h, b); 4 waves x 16 q-rows each. K-tile 64.
// S^T = K  . Q^T  (A=K rows,   B=Q rows)  -> C col(lane15)=q, row=k-pos
//   s[nt][r] = score(q = lane15-row, k = nt*16 + quad*4 + r)  [k-contiguous!]
// P -> per-wave LDS [q][k] (4x ds_write_b64) -> B-frag (2x ds_read_b128)
// O^T = V^T. P^T  -> C col=q, row=d.  Mask tile = MFMA C-init (q/8 folded).
__global__ __launch_bounds__(256) void attn_mfma(
    const u16* __restrict__ qb, const u16* __restrict__ kvb,
    const u16* __restrict__ vt, const float* __restrict__ mask,
    u16* __restrict__ resb)
{
    __shared__ __align__(16) u16 Ks[64][72];
    __shared__ __align__(16) u16 Vs[64][72];      // V^T tile: [d][k]
    __shared__ __align__(16) float Ms[64][68];    // mask tile [q][k], 272B rows
    __shared__ __align__(16) u16 Ps[4][16][72];   // per-wave P [q-local][k]
    const int t = threadIdx.x;
    const int w = t >> 6, l = t & 63;
    const int lane15 = l & 15, quad = l >> 4;
    const int q0 = blockIdx.x * 64;
    const int h = blockIdx.y, b = blockIdx.z;
    const int bh = b * NH + h;
    const int sr = t >> 2, sc = (t & 3) * 16;     // u16 tile staging
    const int mr = t >> 2, mc = (t & 3) * 16;     // mask staging (f32)

    // Q fragments: direct global load, once. (B-operand: n=lane15=q, k=d)
    const u16* qrow = qb + (size_t)(b*SEQ + q0 + w*16 + lane15) * D_MODEL + h*HEAD;
    s16x8 aq0 = *(const s16x8*)(qrow + quad*8);
    s16x8 aq1 = *(const s16x8*)(qrow + 32 + quad*8);

    f32x4 o_acc[4] = {};
    float m_i = -INFINITY, l_i = 0.f;

    for (int k0 = 0; k0 < SEQ; k0 += 64) {
        __syncthreads();
        {   // stage K [k][d], V^T [d][k], mask [q][k]
            const u16* kg = kvb + (size_t)(b*SEQ + k0 + sr) * (2*D_MODEL) + h*128 + sc;
            *(uint4*)&Ks[sr][sc]     = *(const uint4*)kg;
            *(uint4*)&Ks[sr][sc + 8] = *(const uint4*)(kg + 8);
            const u16* vg = vt + (size_t)(bh*64 + sr) * SEQ + k0 + sc;
            *(uint4*)&Vs[sr][sc]     = *(const uint4*)vg;
            *(uint4*)&Vs[sr][sc + 8] = *(const uint4*)(vg + 8);
            const float* mg = mask + ((size_t)b*SEQ + q0 + mr) * SEQ + k0 + mc;
            #pragma unroll
            for (int j = 0; j < 4; ++j)
                *(float4*)&Ms[mr][mc + 4*j] = *(const float4*)(mg + 4*j);
        }
        __syncthreads();

        // S^T: 64(k) x 16(q) per wave, C-init = mask
        f32x4 s[4];
        #pragma unroll
        for (int nt = 0; nt < 4; ++nt) {
            s[nt] = *(const f32x4*)&Ms[w*16 + lane15][nt*16 + quad*4];
            s16x8 k0f = *(const s16x8*)&Ks[nt*16 + lane15][quad*8];
            s16x8 k1f = *(const s16x8*)&Ks[nt*16 + lane15][32 + quad*8];
            s[nt] = __builtin_amdgcn_mfma_f32_16x16x32_bf16(k0f, aq0, s[nt], 0, 0, 0);
            s[nt] = __builtin_amdgcn_mfma_f32_16x16x32_bf16(k1f, aq1, s[nt], 0, 0, 0);
        }

        // online softmax: each lane owns 16 scores of q-row lane15
        float mx = fmaxf(fmaxf(fmaxf(s[0][0], s[0][1]), fmaxf(s[0][2], s[0][3])),
                         fmaxf(fmaxf(s[1][0], s[1][1]), fmaxf(s[1][2], s[1][3])));
        mx = fmaxf(mx, fmaxf(fmaxf(fmaxf(s[2][0], s[2][1]), fmaxf(s[2][2], s[2][3])),
                             fmaxf(fmaxf(s[3][0], s[3][1]), fmaxf(s[3][2], s[3][3]))));
        mx = fmaxf(mx, __shfl_xor(mx, 16));
        mx = fmaxf(mx, __shfl_xor(mx, 32));
        const float mn = fmaxf(m_i, mx);
        const float alpha = __expf(m_i - mn);
        m_i = mn;
        float rs = 0.f;
        #pragma unroll
        for (int nt = 0; nt < 4; ++nt)
            #pragma unroll
            for (int r = 0; r < 4; ++r) {
                float p = __expf(s[nt][r] - mn);
                s[nt][r] = p;
                rs += p;
            }
        rs += __shfl_xor(rs, 16);
        rs += __shfl_xor(rs, 32);
        l_i = l_i * alpha + rs;
        #pragma unroll
        for (int dt = 0; dt < 4; ++dt)
            #pragma unroll
            for (int r = 0; r < 4; ++r)
                o_acc[dt][r] *= alpha;

        // P -> per-wave LDS [q][k] (k-contiguous in C-layout), then B-frags.
        #pragma unroll
        for (int nt = 0; nt < 4; ++nt) {
            ushort4 pv = make_ushort4(tobf(s[nt][0]), tobf(s[nt][1]),
                                      tobf(s[nt][2]), tobf(s[nt][3]));
            *(ushort4*)&Ps[w][lane15][nt*16 + quad*4] = pv;
        }
        s16x8 pf0 = *(const s16x8*)&Ps[w][lane15][quad*8];
        s16x8 pf1 = *(const s16x8*)&Ps[w][lane15][32 + quad*8];
        #pragma unroll
        for (int dt = 0; dt < 4; ++dt) {
            s16x8 vf0 = *(const s16x8*)&Vs[dt*16 + lane15][quad*8];
            s16x8 vf1 = *(const s16x8*)&Vs[dt*16 + lane15][32 + quad*8];
            o_acc[dt] = __builtin_amdgcn_mfma_f32_16x16x32_bf16(vf0, pf0, o_acc[dt], 0, 0, 0);
            o_acc[dt] = __builtin_amdgcn_mfma_f32_16x16x32_bf16(vf1, pf1, o_acc[dt], 0, 0, 0);
        }
    }

    // Epilogue: O^T (col=q, row=d) -> LDS transpose -> coalesced bf16 store
    __syncthreads();
    const float inv = 1.f / l_i;
    #pragma unroll
    for (int dt = 0; dt < 4; ++dt) {
        ushort4 ov = make_ushort4(tobf(o_acc[dt][0]*inv), tobf(o_acc[dt][1]*inv),
                                  tobf(o_acc[dt][2]*inv), tobf(o_acc[dt][3]*inv));
        *(ushort4*)&Ks[w*16 + lane15][dt*16 + quad*4] = ov;
    }
    __syncthreads();
    {
        u16* o = resb + (size_t)(b*SEQ + q0 + sr) * D_MODEL + h*HEAD + sc;
        *(uint4*)o       = *(const uint4*)&Ks[sr][sc];
        *(uint4*)(o + 8) = *(const uint4*)&Ks[sr][sc + 8];
    }
}

extern "C" void kernel_launch(void* const* d_in, const int* in_sizes, int n_in,
                              void* d_out, int out_size, void* d_ws, size_t ws_size,
                              hipStream_t stream) {
    const float* x_enc = (const float*)d_in[0];
    const float* x_dec = (const float*)d_in[1];
    const float* mask  = (const float*)d_in[2];
    const float* Wq    = (const float*)d_in[3];
    const float* bq    = (const float*)d_in[4];
    const float* Wkv   = (const float*)d_in[5];
    const float* bkv   = (const float*)d_in[6];
    const float* Wo    = (const float*)d_in[7];
    const float* bo    = (const float*)d_in[8];
    float* out = (float*)d_out;

    const int M = BATCH * SEQ;  // 8192
    u16* xe   = (u16*)d_ws;                       // 8192x1024
    u16* xd   = xe   + (size_t)M * D_MODEL;       // 8192x1024
    u16* wqT  = xd   + (size_t)M * D_MODEL;       // 1024x1024
    u16* wkvT = wqT  + (size_t)D_MODEL * D_MODEL; // 2048x1024
    u16* woT  = wkvT + (size_t)2*D_MODEL*D_MODEL; // 1024x1024
    u16* qbuf = woT  + (size_t)D_MODEL * D_MODEL; // 8192x1024 (holds Q/8)
    u16* kvb  = qbuf + (size_t)M * D_MODEL;       // 8192x2048
    u16* vtb  = kvb  + (size_t)M * 2 * D_MODEL;   // 64x64x2048
    u16* resb = vtb  + (size_t)BATCH*NH*HEAD*SEQ; // 8192x1024

    const int NX = M * D_MODEL;  // 8388608
    cast_bf16<<<NX/1024, 256, 0, stream>>>(x_enc, xe, NX);
    cast_bf16<<<NX/1024, 256, 0, stream>>>(x_dec, xd, NX);
    transpose_cast<<<dim3(D_MODEL/32, D_MODEL/32), 256, 0, stream>>>(Wq,  wqT,  D_MODEL, D_MODEL);
    transpose_cast<<<dim3(2*D_MODEL/32, D_MODEL/32), 256, 0, stream>>>(Wkv, wkvT, D_MODEL, 2*D_MODEL);
    transpose_cast<<<dim3(D_MODEL/32, D_MODEL/32), 256, 0, stream>>>(Wo,  woT,  D_MODEL, D_MODEL);

    gemm_bt<u16><<<dim3(2*D_MODEL/128, M/128), 256, 0, stream>>>(
        xe, wkvT, bkv, kvb, 2*D_MODEL, D_MODEL, 1.0f);
    gemm_bt<u16><<<dim3(D_MODEL/128, M/128), 256, 0, stream>>>(
        xd, wqT, bq, qbuf, D_MODEL, D_MODEL, 0.125f);   // fold 1/sqrt(HEAD)
    v_transpose<<<dim3(SEQ/64, BATCH*NH), 256, 0, stream>>>(kvb, vtb);
    attn_mfma<<<dim3(SEQ/64, NH, BATCH), 256, 0, stream>>>(
        qbuf, kvb, vtb, mask, resb);
    gemm_bt<float><<<dim3(D_MODEL/128, M/128), 256, 0, stream>>>(
        resb, woT, bo, out, D_MODEL, D_MODEL, 1.0f);
}